// Round 13
// baseline (111.462 us; speedup 1.0000x reference)
//
#include <hip/hip_runtime.h>
#include <math.h>

#define D_IN 512
#define D_HID 128
#define D_OUT 512
#define N_ENT 262144

#define K3_BLOCKS 1024
#define WAVES_PER_BLOCK 8
#define ROWS_PER_BLOCK 256          // N_ENT / K3_BLOCKS
#define ITERS_PER_WAVE 8            // 32 rows per wave, 4 per iteration

// ws float-offsets
#define KV_OFF   0                // 512 floats: kvec pre-scaled by 1/sqrt(H)
#define BM_OFF   512              // 1024 block maxes
#define BS_OFF   1536             // 1024 block sums
#define BT5_OFF_F 2560            // byte 10240 (8B aligned): 1024*5 u64 keys
#define U_OFF    12800            // 512 floats (16B aligned)
#define W_OFF    13312            // 1 float: sum of top5 normalized scores
#define H_OFF    13320            // 128 floats (8B aligned)

#define INV_SQRT_H 0.08838834764831845f  // 1/sqrt(128)

typedef float f32x4 __attribute__((ext_vector_type(4)));
typedef unsigned long long u64;

__device__ inline u64 pack_key(float v, int idx) {
    unsigned u = __float_as_uint(v);
    u = (u & 0x80000000u) ? ~u : (u | 0x80000000u);   // order-preserving
    return ((u64)u << 32) | (unsigned)(~idx);          // ties -> smaller idx wins
}
__device__ inline float unpack_val(u64 k) {
    unsigned o = (unsigned)(k >> 32);
    unsigned u = (o & 0x80000000u) ? (o & 0x7FFFFFFFu) : ~o;
    return __uint_as_float(u);
}
__device__ inline int unpack_idx(u64 k) { return (int)~(unsigned)(k & 0xFFFFFFFFu); }

#define INS5(kk) do { u64 _k = (kk); if (_k > t4) {            \
    if (_k > t0)      { t4=t3;t3=t2;t2=t1;t1=t0;t0=_k; }       \
    else if (_k > t1) { t4=t3;t3=t2;t2=t1;t1=_k; }             \
    else if (_k > t2) { t4=t3;t3=t2;t2=_k; }                   \
    else if (_k > t3) { t4=t3;t3=_k; }                         \
    else              { t4=_k; } } } while (0)

// ---------- K1: fused q = Wq@c+bq (redundant/block) + kvec chunk ----------
__global__ __launch_bounds__(256) void k_front(const float* __restrict__ c,
        const float* __restrict__ Wq, const float* __restrict__ bq,
        const float* __restrict__ Wk, float* __restrict__ ws) {
    __shared__ float qpart[256];
    __shared__ float qs[D_HID];
    __shared__ float kpart[4][64];
    const int t = threadIdx.x;
    {   // phase 1: q[128], 2 threads per h
        const int h = t >> 1, half = t & 1;
        const f32x4* wq = (const f32x4*)(Wq + (h << 9) + (half << 8));
        const f32x4* cv = (const f32x4*)(c + (half << 8));
        float acc = 0.f;
        #pragma unroll 8
        for (int j = 0; j < 64; ++j) {
            f32x4 a = wq[j], b = cv[j];
            acc += a.x*b.x + a.y*b.y + a.z*b.z + a.w*b.w;
        }
        qpart[t] = acc;
    }
    __syncthreads();
    if (t < D_HID) qs[t] = qpart[2*t] + qpart[2*t+1] + bq[t];
    __syncthreads();
    {   // phase 2: kvec[d0..d0+64), wave g covers h in [32g,32g+32)
        const int g = t >> 6, d = t & 63;
        const int d0 = blockIdx.x * 64;
        const float* col = Wk + (size_t)(g * 32) * D_IN + d0 + d;
        float acc = 0.f;
        #pragma unroll 8
        for (int h = 0; h < 32; ++h) acc += col[(size_t)h * D_IN] * qs[g*32 + h];
        kpart[g][d] = acc;
    }
    __syncthreads();
    if (t < 64) {
        float kv = kpart[0][t] + kpart[1][t] + kpart[2][t] + kpart[3][t];
        ws[KV_OFF + blockIdx.x*64 + t] = kv * INV_SQRT_H;   // pre-scale
    }
}

// ---------- K2: logits + online softmax + per-block top5 (packed u64) ----------
// Locality step 3: wave w reads 4 consecutive rows base+4w+32k.. per iter.
// Instantaneous block footprint = 32 contiguous rows (64 KB); 8 loads in
// flight per wave. launch_bounds(512,4): 128-VGPR cap, >=16 waves/CU.
__global__ __launch_bounds__(512, 4) void k_logits(const float* __restrict__ E,
                                                   float* __restrict__ ws) {
    const int t = threadIdx.x;
    const int l = t & 63;
    const int w = t >> 6;
    const long base = (long)blockIdx.x * ROWS_PER_BLOCK;
    const long r0   = base + 4 * w;             // this wave's first row

    const f32x4* kv = (const f32x4*)(ws + KV_OFF);
    const f32x4 k0 = kv[l], k1 = kv[64 + l];

    float m = -INFINITY, s = 0.f;
    u64 t0 = 0, t1 = 0, t2 = 0, t3 = 0, t4 = 0;   // 0 < any real key

    const f32x4* rp = (const f32x4*)(E + r0 * (long)D_IN) + l;
    for (int k = 0; k < ITERS_PER_WAVE; ++k, rp += 4096) {   // +32 rows/iter
        f32x4 a0 = __builtin_nontemporal_load(rp);
        f32x4 a1 = __builtin_nontemporal_load(rp + 64);
        f32x4 b0 = __builtin_nontemporal_load(rp + 128);
        f32x4 b1 = __builtin_nontemporal_load(rp + 192);
        f32x4 c0 = __builtin_nontemporal_load(rp + 256);
        f32x4 c1 = __builtin_nontemporal_load(rp + 320);
        f32x4 e0 = __builtin_nontemporal_load(rp + 384);
        f32x4 e1 = __builtin_nontemporal_load(rp + 448);
        float d0 = a0.x*k0.x + a0.y*k0.y + a0.z*k0.z + a0.w*k0.w
                 + a1.x*k1.x + a1.y*k1.y + a1.z*k1.z + a1.w*k1.w;
        float d1 = b0.x*k0.x + b0.y*k0.y + b0.z*k0.z + b0.w*k0.w
                 + b1.x*k1.x + b1.y*k1.y + b1.z*k1.z + b1.w*k1.w;
        float d2 = c0.x*k0.x + c0.y*k0.y + c0.z*k0.z + c0.w*k0.w
                 + c1.x*k1.x + c1.y*k1.y + c1.z*k1.z + c1.w*k1.w;
        float d3 = e0.x*k0.x + e0.y*k0.y + e0.z*k0.z + e0.w*k0.w
                 + e1.x*k1.x + e1.y*k1.y + e1.z*k1.z + e1.w*k1.w;
        #pragma unroll
        for (int mm = 32; mm > 0; mm >>= 1) {   // four independent chains, ILP
            d0 += __shfl_xor(d0, mm, 64);
            d1 += __shfl_xor(d1, mm, 64);
            d2 += __shfl_xor(d2, mm, 64);
            d3 += __shfl_xor(d3, mm, 64);
        }
        // kvec pre-scaled: d0..d3 ARE the logits
        float nm = fmaxf(fmaxf(m, fmaxf(d0, d1)), fmaxf(d2, d3));
        s = s * __expf(m - nm) + __expf(d0 - nm) + __expf(d1 - nm)
                               + __expf(d2 - nm) + __expf(d3 - nm);
        m = nm;
        const int idx = (int)r0 + 32 * k;
        INS5(pack_key(d0, idx));
        INS5(pack_key(d1, idx + 1));
        INS5(pack_key(d2, idx + 2));
        INS5(pack_key(d3, idx + 3));
    }

    __shared__ float sm[WAVES_PER_BLOCK], ss[WAVES_PER_BLOCK];
    __shared__ u64 skey[WAVES_PER_BLOCK][5];
    if (l == 0) {
        sm[w] = m; ss[w] = s;
        skey[w][0]=t0; skey[w][1]=t1; skey[w][2]=t2; skey[w][3]=t3; skey[w][4]=t4;
    }
    __syncthreads();
    if (t == 0) {
        float M = sm[0];
        #pragma unroll
        for (int j = 1; j < WAVES_PER_BLOCK; ++j) M = fmaxf(M, sm[j]);
        float S = 0.f;
        #pragma unroll
        for (int j = 0; j < WAVES_PER_BLOCK; ++j) S += ss[j] * __expf(sm[j] - M);
        u64 t0=0,t1=0,t2=0,t3=0,t4=0;
        #pragma unroll
        for (int j = 0; j < WAVES_PER_BLOCK*5; ++j) INS5(skey[j/5][j%5]);
        const int b = blockIdx.x;
        ws[BM_OFF + b] = M;
        ws[BS_OFF + b] = S;
        u64* bt = (u64*)ws + (BT5_OFF_F/2) + (size_t)b * 5;
        bt[0]=t0; bt[1]=t1; bt[2]=t2; bt[3]=t3; bt[4]=t4;
    }
}

// ---------- K3: global top5 -> M -> Z -> weights -> u  (1 block x 1024) ----------
__global__ __launch_bounds__(1024) void k_mid(const float* __restrict__ E,
                                              float* __restrict__ ws) {
    __shared__ u64   wc[16][5];
    __shared__ float selv[5];
    __shared__ int   seli[5];
    __shared__ float wn[5];
    __shared__ float zp[16];
    __shared__ float Zsh;
    const int t = threadIdx.x;
    const int l = t & 63;
    const int w = t >> 6;
    const u64* cand = (const u64*)ws + (BT5_OFF_F/2);

    // local top5 over 5 candidates each (1024*5 total)
    u64 t0=0,t1=0,t2=0,t3=0,t4=0;
    #pragma unroll
    for (int j = 0; j < 5; ++j) INS5(cand[t + j*1024]);

    // wave top5: 5 rounds of extract-max (keys unique -> exactly one advancer)
    {
        int pos = 0;
        u64 g0=0,g1=0,g2=0,g3=0,g4=0;
        #pragma unroll
        for (int r = 0; r < 5; ++r) {
            u64 head = pos==0?t0 : pos==1?t1 : pos==2?t2 : pos==3?t3 : pos==4?t4 : 0ULL;
            u64 wm = head;
            #pragma unroll
            for (int mm = 1; mm < 64; mm <<= 1) {
                u64 o = __shfl_xor(wm, mm, 64);
                wm = (o > wm) ? o : wm;
            }
            if (head == wm && wm != 0ULL) pos++;
            if (r==0) g0=wm; else if (r==1) g1=wm; else if (r==2) g2=wm;
            else if (r==3) g3=wm; else g4=wm;
        }
        if (l == 0) { wc[w][0]=g0; wc[w][1]=g1; wc[w][2]=g2; wc[w][3]=g3; wc[w][4]=g4; }
    }
    __syncthreads();

    // cross-wave merge (wave 0; lanes 0..15 present list heads)
    if (t < 64) {
        int pos = 0;
        #pragma unroll
        for (int r = 0; r < 5; ++r) {
            u64 head = (t < 16 && pos < 5) ? wc[t][pos] : 0ULL;
            u64 wm = head;
            #pragma unroll
            for (int mm = 1; mm < 64; mm <<= 1) {
                u64 o = __shfl_xor(wm, mm, 64);
                wm = (o > wm) ? o : wm;
            }
            if (head == wm && wm != 0ULL) pos++;
            if (t == 0) { selv[r] = unpack_val(wm); seli[r] = unpack_idx(wm); }
        }
    }
    __syncthreads();

    const float M = selv[0];   // global max logit == top-1 value

    // Z = sum over blocks of S_b * exp(M_b - M)   (one block per thread)
    {
        float z = ws[BS_OFF + t] * __expf(ws[BM_OFF + t] - M);
        #pragma unroll
        for (int mm = 1; mm < 64; mm <<= 1) z += __shfl_xor(z, mm, 64);
        if (l == 0) zp[w] = z;
    }
    __syncthreads();
    if (t == 0) {
        float Z = 0.f;
        #pragma unroll
        for (int j = 0; j < 16; ++j) Z += zp[j];
        Zsh = Z;
    }
    __syncthreads();
    if (t < 8) {
        float Z = Zsh;
        if (t < 5) wn[t] = __expf(selv[t] - M) / Z;
    }
    __syncthreads();
    if (t == 0) ws[W_OFF] = wn[0]+wn[1]+wn[2]+wn[3]+wn[4];

    // u[d] = sum_r wn[r] * E[idx_r][d]
    if (t < D_IN) {
        float acc = 0.f;
        #pragma unroll
        for (int r = 0; r < 5; ++r)
            acc += wn[r] * E[(long)seli[r] * D_IN + t];
        ws[U_OFF + t] = acc;
    }
}

// ---------- K4: h = Wv @ u + W*bv  (128 blocks x 64) ----------
__global__ void k_h(const float* __restrict__ Wv, const float* __restrict__ bv,
                    float* __restrict__ ws) {
    const int j = blockIdx.x;
    const int l = threadIdx.x;
    const f32x4* row = (const f32x4*)(Wv + (size_t)j * D_IN);
    const f32x4* u   = (const f32x4*)(ws + U_OFF);
    f32x4 a0 = row[l], a1 = row[64 + l];
    f32x4 u0 = u[l],   u1 = u[64 + l];
    float d = a0.x*u0.x + a0.y*u0.y + a0.z*u0.z + a0.w*u0.w
            + a1.x*u1.x + a1.y*u1.y + a1.z*u1.z + a1.w*u1.w;
    #pragma unroll
    for (int m = 32; m > 0; m >>= 1) d += __shfl_xor(d, m, 64);
    if (l == 0) ws[H_OFF + j] = d + ws[W_OFF] * bv[j];
}

// ---------- K5: out = Wo @ h + bo  (512 blocks x 64) ----------
__global__ void k_out(const float* __restrict__ Wo, const float* __restrict__ bo,
                      const float* __restrict__ ws, float* __restrict__ out) {
    const int o = blockIdx.x;
    const int l = threadIdx.x;
    const float2* row = (const float2*)(Wo + (size_t)o * D_HID);
    const float2* h   = (const float2*)(ws + H_OFF);
    float2 a = row[l], hh = h[l];
    float d = a.x*hh.x + a.y*hh.y;
    #pragma unroll
    for (int m = 32; m > 0; m >>= 1) d += __shfl_xor(d, m, 64);
    if (l == 0) out[o] = d + bo[o];
}

extern "C" void kernel_launch(void* const* d_in, const int* in_sizes, int n_in,
                              void* d_out, int out_size, void* d_ws, size_t ws_size,
                              hipStream_t stream) {
    const float* c  = (const float*)d_in[0];
    const float* E  = (const float*)d_in[1];
    const float* Wq = (const float*)d_in[2];
    const float* bq = (const float*)d_in[3];
    const float* Wk = (const float*)d_in[4];
    // d_in[5] = bk: uniform logit shift, cancels in softmax
    const float* Wv = (const float*)d_in[6];
    const float* bv = (const float*)d_in[7];
    const float* Wo = (const float*)d_in[8];
    const float* bo = (const float*)d_in[9];
    // d_in[10] = top_k (always 5)
    float* ws  = (float*)d_ws;
    float* out = (float*)d_out;

    hipLaunchKernelGGL(k_front,  dim3(8),         dim3(256),  0, stream, c, Wq, bq, Wk, ws);
    hipLaunchKernelGGL(k_logits, dim3(K3_BLOCKS), dim3(512),  0, stream, E, ws);
    hipLaunchKernelGGL(k_mid,    dim3(1),         dim3(1024), 0, stream, E, ws);
    hipLaunchKernelGGL(k_h,      dim3(128),       dim3(64),   0, stream, Wv, bv, ws);
    hipLaunchKernelGGL(k_out,    dim3(512),       dim3(64),   0, stream, Wo, bo, ws, out);
}

// Round 14
// 110.459 us; speedup vs baseline: 1.0091x; 1.0091x over previous
//
#include <hip/hip_runtime.h>
#include <math.h>

#define D_IN 512
#define D_HID 128
#define D_OUT 512
#define N_ENT 262144

#define K3_BLOCKS 1024
#define WAVES_PER_BLOCK 8
#define ROWS_PER_BLOCK 256          // N_ENT / K3_BLOCKS
#define PAIRS_PER_WAVE 16           // 32 rows per wave, 2 per iteration

// ws float-offsets
#define KV_OFF   0                // 512 floats: kvec pre-scaled by 1/sqrt(H)
#define BM_OFF   512              // 1024 block maxes
#define BS_OFF   1536             // 1024 block sums
#define BT5_OFF_F 2560            // byte 10240 (8B aligned): 1024*5 u64 keys
#define U_OFF    12800            // 512 floats (16B aligned)
#define W_OFF    13312            // 1 float: sum of top5 normalized scores
#define H_OFF    13320            // 128 floats (8B aligned)

#define INV_SQRT_H 0.08838834764831845f  // 1/sqrt(128)

typedef float f32x4 __attribute__((ext_vector_type(4)));
typedef unsigned long long u64;

__device__ inline u64 pack_key(float v, int idx) {
    unsigned u = __float_as_uint(v);
    u = (u & 0x80000000u) ? ~u : (u | 0x80000000u);   // order-preserving
    return ((u64)u << 32) | (unsigned)(~idx);          // ties -> smaller idx wins
}
__device__ inline float unpack_val(u64 k) {
    unsigned o = (unsigned)(k >> 32);
    unsigned u = (o & 0x80000000u) ? (o & 0x7FFFFFFFu) : ~o;
    return __uint_as_float(u);
}
__device__ inline int unpack_idx(u64 k) { return (int)~(unsigned)(k & 0xFFFFFFFFu); }

#define INS5(kk) do { u64 _k = (kk); if (_k > t4) {            \
    if (_k > t0)      { t4=t3;t3=t2;t2=t1;t1=t0;t0=_k; }       \
    else if (_k > t1) { t4=t3;t3=t2;t2=t1;t1=_k; }             \
    else if (_k > t2) { t4=t3;t3=t2;t2=_k; }                   \
    else if (_k > t3) { t4=t3;t3=_k; }                         \
    else              { t4=_k; } } } while (0)

// ---------- K1: fused q = Wq@c+bq (redundant/block) + kvec chunk ----------
__global__ __launch_bounds__(256) void k_front(const float* __restrict__ c,
        const float* __restrict__ Wq, const float* __restrict__ bq,
        const float* __restrict__ Wk, float* __restrict__ ws) {
    __shared__ float qpart[256];
    __shared__ float qs[D_HID];
    __shared__ float kpart[4][64];
    const int t = threadIdx.x;
    {   // phase 1: q[128], 2 threads per h
        const int h = t >> 1, half = t & 1;
        const f32x4* wq = (const f32x4*)(Wq + (h << 9) + (half << 8));
        const f32x4* cv = (const f32x4*)(c + (half << 8));
        float acc = 0.f;
        #pragma unroll 8
        for (int j = 0; j < 64; ++j) {
            f32x4 a = wq[j], b = cv[j];
            acc += a.x*b.x + a.y*b.y + a.z*b.z + a.w*b.w;
        }
        qpart[t] = acc;
    }
    __syncthreads();
    if (t < D_HID) qs[t] = qpart[2*t] + qpart[2*t+1] + bq[t];
    __syncthreads();
    {   // phase 2: kvec[d0..d0+64), wave g covers h in [32g,32g+32)
        const int g = t >> 6, d = t & 63;
        const int d0 = blockIdx.x * 64;
        const float* col = Wk + (size_t)(g * 32) * D_IN + d0 + d;
        float acc = 0.f;
        #pragma unroll 8
        for (int h = 0; h < 32; ++h) acc += col[(size_t)h * D_IN] * qs[g*32 + h];
        kpart[g][d] = acc;
    }
    __syncthreads();
    if (t < 64) {
        float kv = kpart[0][t] + kpart[1][t] + kpart[2][t] + kpart[3][t];
        ws[KV_OFF + blockIdx.x*64 + t] = kv * INV_SQRT_H;   // pre-scale
    }
}

// ---------- K2: logits + online softmax + per-block top5 (packed u64) ----------
// Measured-best (R12): 512-thread blocks (8 waves), 1024 blocks. Wave w takes
// row pairs base + 2w + 16k -> at any instant the block's 8 waves read 16
// contiguous rows (32 KB burst); 1024 sequential streams. Locality curve
// saturates here (R11: +9us, R12: +1.8us, R13 64KB step: -1.3us).
__global__ __launch_bounds__(512, 8) void k_logits(const float* __restrict__ E,
                                                   float* __restrict__ ws) {
    const int t = threadIdx.x;
    const int l = t & 63;
    const int w = t >> 6;
    const long base = (long)blockIdx.x * ROWS_PER_BLOCK;
    const long r0   = base + 2 * w;             // this wave's first row

    const f32x4* kv = (const f32x4*)(ws + KV_OFF);
    const f32x4 k0 = kv[l], k1 = kv[64 + l];

    float m = -INFINITY, s = 0.f;
    u64 t0 = 0, t1 = 0, t2 = 0, t3 = 0, t4 = 0;   // 0 < any real key

    const f32x4* rp = (const f32x4*)(E + r0 * (long)D_IN) + l;
    for (int k = 0; k < PAIRS_PER_WAVE; ++k, rp += 2048) {   // +16 rows/iter
        f32x4 a0 = __builtin_nontemporal_load(rp);
        f32x4 a1 = __builtin_nontemporal_load(rp + 64);
        f32x4 b0 = __builtin_nontemporal_load(rp + 128);
        f32x4 b1 = __builtin_nontemporal_load(rp + 192);
        float d0 = a0.x*k0.x + a0.y*k0.y + a0.z*k0.z + a0.w*k0.w
                 + a1.x*k1.x + a1.y*k1.y + a1.z*k1.z + a1.w*k1.w;
        float d1 = b0.x*k0.x + b0.y*k0.y + b0.z*k0.z + b0.w*k0.w
                 + b1.x*k1.x + b1.y*k1.y + b1.z*k1.z + b1.w*k1.w;
        #pragma unroll
        for (int mm = 32; mm > 0; mm >>= 1) {   // two independent chains, ILP
            d0 += __shfl_xor(d0, mm, 64);
            d1 += __shfl_xor(d1, mm, 64);
        }
        // kvec pre-scaled: d0/d1 ARE the logits
        float nm = fmaxf(m, fmaxf(d0, d1));
        s = s * __expf(m - nm) + __expf(d0 - nm) + __expf(d1 - nm);
        m = nm;
        const int idx = (int)r0 + 16 * k;
        INS5(pack_key(d0, idx));
        INS5(pack_key(d1, idx + 1));
    }

    __shared__ float sm[WAVES_PER_BLOCK], ss[WAVES_PER_BLOCK];
    __shared__ u64 skey[WAVES_PER_BLOCK][5];
    if (l == 0) {
        sm[w] = m; ss[w] = s;
        skey[w][0]=t0; skey[w][1]=t1; skey[w][2]=t2; skey[w][3]=t3; skey[w][4]=t4;
    }
    __syncthreads();
    if (t == 0) {
        float M = sm[0];
        #pragma unroll
        for (int j = 1; j < WAVES_PER_BLOCK; ++j) M = fmaxf(M, sm[j]);
        float S = 0.f;
        #pragma unroll
        for (int j = 0; j < WAVES_PER_BLOCK; ++j) S += ss[j] * __expf(sm[j] - M);
        u64 t0=0,t1=0,t2=0,t3=0,t4=0;
        #pragma unroll
        for (int j = 0; j < WAVES_PER_BLOCK*5; ++j) INS5(skey[j/5][j%5]);
        const int b = blockIdx.x;
        ws[BM_OFF + b] = M;
        ws[BS_OFF + b] = S;
        u64* bt = (u64*)ws + (BT5_OFF_F/2) + (size_t)b * 5;
        bt[0]=t0; bt[1]=t1; bt[2]=t2; bt[3]=t3; bt[4]=t4;
    }
}

// ---------- K3: global top5 -> M -> Z -> weights -> u  (1 block x 1024) ----------
__global__ __launch_bounds__(1024) void k_mid(const float* __restrict__ E,
                                              float* __restrict__ ws) {
    __shared__ u64   wc[16][5];
    __shared__ float selv[5];
    __shared__ int   seli[5];
    __shared__ float wn[5];
    __shared__ float zp[16];
    __shared__ float Zsh;
    const int t = threadIdx.x;
    const int l = t & 63;
    const int w = t >> 6;
    const u64* cand = (const u64*)ws + (BT5_OFF_F/2);

    // local top5 over 5 candidates each (1024*5 total)
    u64 t0=0,t1=0,t2=0,t3=0,t4=0;
    #pragma unroll
    for (int j = 0; j < 5; ++j) INS5(cand[t + j*1024]);

    // wave top5: 5 rounds of extract-max (keys unique -> exactly one advancer)
    {
        int pos = 0;
        u64 g0=0,g1=0,g2=0,g3=0,g4=0;
        #pragma unroll
        for (int r = 0; r < 5; ++r) {
            u64 head = pos==0?t0 : pos==1?t1 : pos==2?t2 : pos==3?t3 : pos==4?t4 : 0ULL;
            u64 wm = head;
            #pragma unroll
            for (int mm = 1; mm < 64; mm <<= 1) {
                u64 o = __shfl_xor(wm, mm, 64);
                wm = (o > wm) ? o : wm;
            }
            if (head == wm && wm != 0ULL) pos++;
            if (r==0) g0=wm; else if (r==1) g1=wm; else if (r==2) g2=wm;
            else if (r==3) g3=wm; else g4=wm;
        }
        if (l == 0) { wc[w][0]=g0; wc[w][1]=g1; wc[w][2]=g2; wc[w][3]=g3; wc[w][4]=g4; }
    }
    __syncthreads();

    // cross-wave merge (wave 0; lanes 0..15 present list heads)
    if (t < 64) {
        int pos = 0;
        #pragma unroll
        for (int r = 0; r < 5; ++r) {
            u64 head = (t < 16 && pos < 5) ? wc[t][pos] : 0ULL;
            u64 wm = head;
            #pragma unroll
            for (int mm = 1; mm < 64; mm <<= 1) {
                u64 o = __shfl_xor(wm, mm, 64);
                wm = (o > wm) ? o : wm;
            }
            if (head == wm && wm != 0ULL) pos++;
            if (t == 0) { selv[r] = unpack_val(wm); seli[r] = unpack_idx(wm); }
        }
    }
    __syncthreads();

    const float M = selv[0];   // global max logit == top-1 value

    // Z = sum over blocks of S_b * exp(M_b - M)   (one block per thread)
    {
        float z = ws[BS_OFF + t] * __expf(ws[BM_OFF + t] - M);
        #pragma unroll
        for (int mm = 1; mm < 64; mm <<= 1) z += __shfl_xor(z, mm, 64);
        if (l == 0) zp[w] = z;
    }
    __syncthreads();
    if (t == 0) {
        float Z = 0.f;
        #pragma unroll
        for (int j = 0; j < 16; ++j) Z += zp[j];
        Zsh = Z;
    }
    __syncthreads();
    if (t < 8) {
        float Z = Zsh;
        if (t < 5) wn[t] = __expf(selv[t] - M) / Z;
    }
    __syncthreads();
    if (t == 0) ws[W_OFF] = wn[0]+wn[1]+wn[2]+wn[3]+wn[4];

    // u[d] = sum_r wn[r] * E[idx_r][d]
    if (t < D_IN) {
        float acc = 0.f;
        #pragma unroll
        for (int r = 0; r < 5; ++r)
            acc += wn[r] * E[(long)seli[r] * D_IN + t];
        ws[U_OFF + t] = acc;
    }
}

// ---------- K4: h = Wv @ u + W*bv  (128 blocks x 64) ----------
__global__ void k_h(const float* __restrict__ Wv, const float* __restrict__ bv,
                    float* __restrict__ ws) {
    const int j = blockIdx.x;
    const int l = threadIdx.x;
    const f32x4* row = (const f32x4*)(Wv + (size_t)j * D_IN);
    const f32x4* u   = (const f32x4*)(ws + U_OFF);
    f32x4 a0 = row[l], a1 = row[64 + l];
    f32x4 u0 = u[l],   u1 = u[64 + l];
    float d = a0.x*u0.x + a0.y*u0.y + a0.z*u0.z + a0.w*u0.w
            + a1.x*u1.x + a1.y*u1.y + a1.z*u1.z + a1.w*u1.w;
    #pragma unroll
    for (int m = 32; m > 0; m >>= 1) d += __shfl_xor(d, m, 64);
    if (l == 0) ws[H_OFF + j] = d + ws[W_OFF] * bv[j];
}

// ---------- K5: out = Wo @ h + bo  (512 blocks x 64) ----------
__global__ void k_out(const float* __restrict__ Wo, const float* __restrict__ bo,
                      const float* __restrict__ ws, float* __restrict__ out) {
    const int o = blockIdx.x;
    const int l = threadIdx.x;
    const float2* row = (const float2*)(Wo + (size_t)o * D_HID);
    const float2* h   = (const float2*)(ws + H_OFF);
    float2 a = row[l], hh = h[l];
    float d = a.x*hh.x + a.y*hh.y;
    #pragma unroll
    for (int m = 32; m > 0; m >>= 1) d += __shfl_xor(d, m, 64);
    if (l == 0) out[o] = d + bo[o];
}

extern "C" void kernel_launch(void* const* d_in, const int* in_sizes, int n_in,
                              void* d_out, int out_size, void* d_ws, size_t ws_size,
                              hipStream_t stream) {
    const float* c  = (const float*)d_in[0];
    const float* E  = (const float*)d_in[1];
    const float* Wq = (const float*)d_in[2];
    const float* bq = (const float*)d_in[3];
    const float* Wk = (const float*)d_in[4];
    // d_in[5] = bk: uniform logit shift, cancels in softmax
    const float* Wv = (const float*)d_in[6];
    const float* bv = (const float*)d_in[7];
    const float* Wo = (const float*)d_in[8];
    const float* bo = (const float*)d_in[9];
    // d_in[10] = top_k (always 5)
    float* ws  = (float*)d_ws;
    float* out = (float*)d_out;

    hipLaunchKernelGGL(k_front,  dim3(8),         dim3(256),  0, stream, c, Wq, bq, Wk, ws);
    hipLaunchKernelGGL(k_logits, dim3(K3_BLOCKS), dim3(512),  0, stream, E, ws);
    hipLaunchKernelGGL(k_mid,    dim3(1),         dim3(1024), 0, stream, E, ws);
    hipLaunchKernelGGL(k_h,      dim3(128),       dim3(64),   0, stream, Wv, bv, ws);
    hipLaunchKernelGGL(k_out,    dim3(512),       dim3(64),   0, stream, Wo, bo, ws, out);
}